// Round 19
// baseline (315.247 us; speedup 1.0000x reference)
//
#include <hip/hip_runtime.h>

#define BB 8
#define HH 48
#define WW2 48
#define LL 2304      // HH*WW2
#define CIN 192
#define DI 384
#define NK 4
#define RR 12
#define NS 16
#define CD 44        // RR + 2*NS
#define NX 176       // NK*CD, xdbl row width (spatial layout)
#define MM 18432     // BB*LL
#define NC 48        // scan chunks
#define CL 48        // LL/NC

typedef unsigned short u16;
typedef __attribute__((ext_vector_type(8))) short s16x8;
typedef __attribute__((ext_vector_type(4))) float f32x4;
typedef __attribute__((ext_vector_type(2))) float f32x2;

#if __has_builtin(__builtin_elementwise_fma)
#define EFMA(a, b, c) __builtin_elementwise_fma((a), (b), (c))
#else
#define EFMA(a, b, c) ((a) * (b) + (c))
#endif

static __device__ __forceinline__ float siluf(float x) { return x / (1.f + __expf(-x)); }

static __device__ __forceinline__ u16 f2bf(float x) {
    unsigned u = __float_as_uint(x);
    return (u16)((u + 0x7FFFu + ((u >> 16) & 1u)) >> 16);
}
static __device__ __forceinline__ float bf2f(u16 h) {
    return __uint_as_float(((unsigned)h) << 16);
}

// scan index l (direction k) -> row-major spatial position
static __device__ __forceinline__ int posmap(int k, int l) {
    switch (k & 3) {
    case 0: return l;
    case 1: { int w = l / HH; int h = l - w * HH; return h * WW2 + w; }
    case 2: return LL - 1 - l;
    default: { int j = LL - 1 - l; int w = j / HH; int h = j - w * HH; return h * WW2 + w; }
    }
}

// ---------------- merged weight converter: 3 weights -> bf16 hi/lo planes ----------------
#define W0N 147456   // in_proj_w 768*192
#define W1N 67584    // x_proj_w 176*384
#define W2N 73728    // out_proj_w 192*384
__global__ __launch_bounds__(256) void k_cvtw(const float* __restrict__ w0,
                                              const float* __restrict__ w1,
                                              const float* __restrict__ w2,
                                              u16* __restrict__ wpl) {
    int i = (blockIdx.x * 256 + threadIdx.x) * 4;
    const float* src; u16* hi; u16* lo; int base;
    if (i < W0N)                { src = w0; hi = wpl;          lo = wpl + 147456; base = i; }
    else if (i < W0N + W1N)     { src = w1; hi = wpl + 294912; lo = wpl + 362496; base = i - W0N; }
    else if (i < W0N + W1N + W2N) { src = w2; hi = wpl + 430080; lo = wpl + 503808; base = i - W0N - W1N; }
    else return;
    float4 v = *(const float4*)(src + base);
    u16 h0 = f2bf(v.x), h1 = f2bf(v.y), h2 = f2bf(v.z), h3 = f2bf(v.w);
    hi[base + 0] = h0; hi[base + 1] = h1; hi[base + 2] = h2; hi[base + 3] = h3;
    lo[base + 0] = f2bf(v.x - bf2f(h0));
    lo[base + 1] = f2bf(v.y - bf2f(h1));
    lo[base + 2] = f2bf(v.z - bf2f(h2));
    lo[base + 3] = f2bf(v.w - bf2f(h3));
}

// ---------------- split-bf16 MFMA GEMM, tile 128x64: C(M x N) = A(M x K) @ B(N x K)^T ----------------
// EPI: 0 = in_proj (split xi fp32 / silu->zb bf16), 1 = store N=176 guarded, 2 = plain store (CIN).
// ACVT: 0 = A is bf16 plane(s); 1 = A fp32 split on the fly.
// SPLIT: 1 = Ah*Bh only; 2 = Al*Bh + Ah*Bh.
template<int N, int K, int EPI, int ACVT, int SPLIT>
__global__ __launch_bounds__(256) void k_gemm(const u16* __restrict__ Ahg,
                                              const u16* __restrict__ Alg,
                                              const u16* __restrict__ Bhg,
                                              float* __restrict__ O1,
                                              void* __restrict__ O2) {
    // u16 idx: Ah[0,4096) Al[4096,8192) Bh[8192,10240)
    __shared__ __align__(16) u16 lds[10240];
    const int m0 = blockIdx.x << 7;
    const int n0 = blockIdx.y << 6;
    const int t = threadIdx.x;
    const int lane = t & 63;
    const int w = t >> 6;
    const int wm = w & 1, wn = w >> 1;

    f32x4 acc[4][2];
#pragma unroll
    for (int mi = 0; mi < 4; ++mi)
#pragma unroll
        for (int ni = 0; ni < 2; ++ni)
#pragma unroll
            for (int r = 0; r < 4; ++r) acc[mi][ni][r] = 0.f;

    const int rA = lane & 15;
    const int kb = (lane >> 4) << 3;

    for (int k0 = 0; k0 < K; k0 += 32) {
#pragma unroll
        for (int rep = 0; rep < 2; ++rep) {
            int q = t + (rep << 8);
            int row = q >> 2;
            int kk = (q & 3) << 3;
            size_t ga = (size_t)(m0 + row) * K + k0 + kk;
            if (ACVT == 1) {
                const float* Af = (const float*)Ahg;
                float vv[8];
                *(float4*)(vv + 0) = *(const float4*)(Af + ga);
                *(float4*)(vv + 4) = *(const float4*)(Af + ga + 4);
                u16 hbuf[8], lbuf[8];
#pragma unroll
                for (int i = 0; i < 8; ++i) {
                    u16 h = f2bf(vv[i]);
                    hbuf[i] = h;
                    lbuf[i] = f2bf(vv[i] - bf2f(h));
                }
                *(uint4*)&lds[(row << 5) + kk] = *(uint4*)hbuf;
                if (SPLIT == 2)
                    *(uint4*)&lds[4096 + (row << 5) + kk] = *(uint4*)lbuf;
            } else {
                *(uint4*)&lds[(row << 5) + kk] = *(const uint4*)(Ahg + ga);
                if (SPLIT == 2)
                    *(uint4*)&lds[4096 + (row << 5) + kk] = *(const uint4*)(Alg + ga);
            }
        }
        {
            int row = t >> 2;
            int kk = (t & 3) << 3;
            int rg = n0 + row;
            if (N & 63) rg = (rg > N - 1) ? (N - 1) : rg;   // clamp (garbage cols unstored)
            size_t gb = (size_t)rg * K + k0 + kk;
            *(uint4*)&lds[8192 + (row << 5) + kk] = *(const uint4*)(Bhg + gb);
        }
        __syncthreads();

        s16x8 bh[2];
#pragma unroll
        for (int ni = 0; ni < 2; ++ni) {
            int c = (wn << 5) + (ni << 4) + rA;
            bh[ni] = *(const s16x8*)&lds[8192 + (c << 5) + kb];
        }
#pragma unroll
        for (int mi = 0; mi < 4; ++mi) {
            int rr = (wm << 6) + (mi << 4) + rA;
            s16x8 ah = *(const s16x8*)&lds[(rr << 5) + kb];
#pragma unroll
            for (int ni = 0; ni < 2; ++ni) {
                if (SPLIT == 2) {
                    s16x8 al = *(const s16x8*)&lds[4096 + (rr << 5) + kb];
                    acc[mi][ni] = __builtin_amdgcn_mfma_f32_16x16x32_bf16(al, bh[ni], acc[mi][ni], 0, 0, 0);
                }
                acc[mi][ni] = __builtin_amdgcn_mfma_f32_16x16x32_bf16(ah, bh[ni], acc[mi][ni], 0, 0, 0);
            }
        }
        __syncthreads();
    }

    const int rbase = (lane >> 4) << 2;
#pragma unroll
    for (int mi = 0; mi < 4; ++mi) {
#pragma unroll
        for (int ni = 0; ni < 2; ++ni) {
            int o = n0 + (wn << 5) + (ni << 4) + (lane & 15);
#pragma unroll
            for (int r = 0; r < 4; ++r) {
                int m = m0 + (wm << 6) + (mi << 4) + rbase + r;
                float v = acc[mi][ni][r];
                if (EPI == 0) {
                    if (o < DI) O1[(size_t)m * DI + o] = v;
                    else        ((u16*)O2)[(size_t)m * DI + (o - DI)] = f2bf(siluf(v));
                } else if (EPI == 1) {
                    if (o < NX) O1[(size_t)m * NX + o] = v;
                } else {
                    O1[(size_t)m * CIN + o] = v;
                }
            }
        }
    }
}

// ---------------- depthwise 3x3 conv + silu (NHWC, float2 over d) -> ub fp32 only ----------------
__global__ __launch_bounds__(192) void k_conv(const float* __restrict__ xi,
                                              const float* __restrict__ cw,
                                              const float* __restrict__ cb,
                                              float* __restrict__ ub) {
    int blk = blockIdx.x;
    int b = blk / LL, p = blk - b * LL;
    int h = p / WW2, w = p - h * WW2;
    int d2 = threadIdx.x * 2;

    float w0[9], w1[9];
#pragma unroll
    for (int i = 0; i < 9; ++i) {
        w0[i] = cw[d2 * 9 + i];
        w1[i] = cw[(d2 + 1) * 9 + i];
    }
    float ax = cb[d2], ay = cb[d2 + 1];
#pragma unroll
    for (int dh = -1; dh <= 1; ++dh) {
        int hh = h + dh;
        if (hh < 0 || hh >= HH) continue;
#pragma unroll
        for (int dw = -1; dw <= 1; ++dw) {
            int ww = w + dw;
            if (ww < 0 || ww >= WW2) continue;
            float2 v = *(const float2*)(xi + ((size_t)b * LL + hh * WW2 + ww) * DI + d2);
            int tap = (dh + 1) * 3 + (dw + 1);
            ax = fmaf(w0[tap], v.x, ax);
            ay = fmaf(w1[tap], v.y, ay);
        }
    }
    float2 o2; o2.x = siluf(ax); o2.y = siluf(ay);
    *(float2*)(ub + ((size_t)b * LL + p) * DI + d2) = o2;
}

// p-advance for one scan step (l -> l+1); k uniform per block
static __device__ __forceinline__ void adv_p(int k, int& p, int& hh) {
    if (k == 0) { ++p; }
    else if (k == 2) { --p; }
    else if (k == 1) {
        bool wrap = (hh == HH - 1);
        hh = wrap ? 0 : hh + 1;
        p += wrap ? -(LL - 1 - HH) : WW2;
    } else {
        bool wrap = (hh == 0);
        hh = wrap ? HH - 1 : hh - 1;
        p += wrap ? (LL - 1 - HH) : -WW2;
    }
}

static __device__ __forceinline__ void init_p(int k, int l0, int& p, int& hh) {
    hh = 0;
    if (k == 0) p = l0;
    else if (k == 2) p = LL - 1 - l0;
    else if (k == 1) { int w0 = l0 / HH; hh = l0 - w0 * HH; p = hh * WW2 + w0; }
    else { int j0 = LL - 1 - l0; int w0 = j0 / HH; hh = j0 - w0 * HH; p = hh * WW2 + w0; }
}

// scan grid decode: blk = ((k*3 + dblk)*NC + c)*8 + b  -> b = blk & 7 pins batch to XCD
static __device__ __forceinline__ void scan_decode(int blk, int& b, int& k, int& dblk, int& c) {
    b = blk & 7;
    int r = blk >> 3;
    c = r % NC;
    int t2 = r / NC;
    dblk = t2 % 3;
    k = t2 / 3;
}

// ---------------- scan S1: per-chunk local scan, store h_fin[16] + sum_dt ----------------
__global__ __launch_bounds__(128) void k_scan1(const float* __restrict__ ub,
                                               const float* __restrict__ xdbl,
                                               const float* __restrict__ dt_w,
                                               const float* __restrict__ dt_bias,
                                               const float* __restrict__ A_logs,
                                               float* __restrict__ HF,
                                               float* __restrict__ SD) {
    int b, k, dblk, c;
    scan_decode(blockIdx.x, b, k, dblk, c);
    int bk = (b << 2) | k;
    int d = (dblk << 7) + threadIdx.x;
    int kd = k * DI + d;

    float dtw[RR];
#pragma unroll
    for (int r = 0; r < RR; ++r) dtw[r] = dt_w[(size_t)kd * RR + r];
    float dtb = dt_bias[kd];
    float a[NS];
    bool fast = true;
#pragma unroll
    for (int n = 0; n < NS; ++n) {
        a[n] = -__expf(A_logs[(size_t)kd * NS + n]);
        fast = fast && (fabsf(a[n] + (float)(n + 1)) < 1e-3f * (float)(n + 1));
    }
    int use_fast = __all((int)fast);

    f32x2 h2[8];
#pragma unroll
    for (int i = 0; i < 8; ++i) { h2[i][0] = 0.f; h2[i][1] = 0.f; }
    float sumdt = 0.f;

    const float* cb0 = xdbl + (size_t)b * LL * NX + k * CD;   // row at spatial p: cb0 + p*NX
    const float* ubase = ub + (size_t)b * LL * DI + d;
    const int l0 = c * CL;
    int p, hh;
    init_p(k, l0, p, hh);

    if (use_fast) {
        int pcur = p;
        float uv = ubase[(size_t)pcur * DI];
        for (int li = 0; li < CL; ++li) {
            // advance and issue next u-load early (overlaps dt-head + state math)
            adv_p(k, p, hh);
            int pn = (li + 1 < CL) ? p : pcur;
            float uv_next = ubase[(size_t)pn * DI];

            const float4* cp4 = (const float4*)(cb0 + (size_t)pcur * NX);
            float dq[12];
            *(float4*)(dq + 0) = cp4[0];
            *(float4*)(dq + 4) = cp4[1];
            *(float4*)(dq + 8) = cp4[2];
            float s = dtb;
#pragma unroll
            for (int r = 0; r < RR; ++r) s = fmaf(dtw[r], dq[r], s);
            float es = __expf(s);
            float dt = (s > 15.f) ? s : __logf(1.f + es);
            float E = __builtin_amdgcn_rcpf(1.f + es);
            sumdt += dt;
            float du = dt * uv;
            float bb2[16];
            *(float4*)(bb2 + 0)  = cp4[3];
            *(float4*)(bb2 + 4)  = cp4[4];
            *(float4*)(bb2 + 8)  = cp4[5];
            *(float4*)(bb2 + 12) = cp4[6];
            const f32x2* b2 = (const f32x2*)bb2;
            float ee = E * E;
            f32x2 pw2; pw2[0] = E; pw2[1] = ee;
            f32x2 ee2; ee2[0] = ee; ee2[1] = ee;
            f32x2 du2; du2[0] = du; du2[1] = du;
#pragma unroll
            for (int i = 0; i < 8; ++i) {
                h2[i] = EFMA(du2, b2[i], pw2 * h2[i]);
                if (i < 7) pw2 = pw2 * ee2;
            }
            pcur = p;
            uv = uv_next;
        }
    } else {
        for (int li = 0; li < CL; ++li) {
            int l = l0 + li;
            int pp = posmap(k, l);
            const float* cp = cb0 + (size_t)pp * NX;
            float s = dtb;
#pragma unroll
            for (int r = 0; r < RR; ++r) s = fmaf(dtw[r], cp[r], s);
            float dt = (s > 15.f) ? s : log1pf(__expf(s));
            sumdt += dt;
            float uv = ubase[(size_t)pp * DI];
            float du = dt * uv;
#pragma unroll
            for (int n = 0; n < NS; ++n) {
                float dA = __expf(dt * a[n]);
                float hv = h2[n >> 1][n & 1];
                h2[n >> 1][n & 1] = fmaf(du, cp[RR + n], dA * hv);
            }
        }
    }
    size_t base = ((size_t)bk * NC + c);
#pragma unroll
    for (int i = 0; i < 8; ++i) {
        HF[(base * NS + 2 * i) * DI + d] = h2[i][0];
        HF[(base * NS + 2 * i + 1) * DI + d] = h2[i][1];
    }
    SD[base * DI + d] = sumdt;
}

// ---------------- scan S2: combine chunk states -> entry states (in place) ----------------
__global__ __launch_bounds__(256) void k_scan2(const float* __restrict__ A_logs,
                                               float* __restrict__ HF,
                                               const float* __restrict__ SD) {
    int idx = blockIdx.x * 256 + threadIdx.x;    // bk*DI + d
    int bk = idx / DI;
    int d = idx - bk * DI;
    int k = bk & 3;
    int kd = k * DI + d;

    float a[NS];
    bool fast = true;
#pragma unroll
    for (int n = 0; n < NS; ++n) {
        a[n] = -__expf(A_logs[(size_t)kd * NS + n]);
        fast = fast && (fabsf(a[n] + (float)(n + 1)) < 1e-3f * (float)(n + 1));
    }
    int use_fast = __all((int)fast);

    float H[NS];
#pragma unroll
    for (int n = 0; n < NS; ++n) H[n] = 0.f;

    for (int c = 0; c < NC; ++c) {
        size_t base = ((size_t)bk * NC + c);
        float sd = SD[base * DI + d];
        if (use_fast) {
            float E = __expf(-sd);
            float pw = 1.f;
#pragma unroll
            for (int n = 0; n < NS; ++n) {
                pw *= E;
                float hf = HF[(base * NS + n) * DI + d];
                HF[(base * NS + n) * DI + d] = H[n];
                H[n] = fmaf(pw, H[n], hf);
            }
        } else {
#pragma unroll
            for (int n = 0; n < NS; ++n) {
                float dec = __expf(a[n] * sd);
                float hf = HF[(base * NS + n) * DI + d];
                HF[(base * NS + n) * DI + d] = H[n];
                H[n] = fmaf(dec, H[n], hf);
            }
        }
    }
}

// ---------------- scan S3: per-chunk scan from entry state, scatter y ----------------
__global__ __launch_bounds__(128) void k_scan3(const float* __restrict__ ub,
                                               const float* __restrict__ xdbl,
                                               const float* __restrict__ dt_w,
                                               const float* __restrict__ dt_bias,
                                               const float* __restrict__ A_logs,
                                               const float* __restrict__ Ds,
                                               const float* __restrict__ HF,
                                               float* __restrict__ ycomb) {
    int b, k, dblk, c;
    scan_decode(blockIdx.x, b, k, dblk, c);
    int bk = (b << 2) | k;
    int d = (dblk << 7) + threadIdx.x;
    int kd = k * DI + d;

    float dtw[RR];
#pragma unroll
    for (int r = 0; r < RR; ++r) dtw[r] = dt_w[(size_t)kd * RR + r];
    float dtb = dt_bias[kd];
    float dsv = Ds[kd];
    float a[NS];
    bool fast = true;
#pragma unroll
    for (int n = 0; n < NS; ++n) {
        a[n] = -__expf(A_logs[(size_t)kd * NS + n]);
        fast = fast && (fabsf(a[n] + (float)(n + 1)) < 1e-3f * (float)(n + 1));
    }
    int use_fast = __all((int)fast);

    f32x2 h2[8];
    size_t sbase = ((size_t)bk * NC + c);
#pragma unroll
    for (int i = 0; i < 8; ++i) {
        h2[i][0] = HF[(sbase * NS + 2 * i) * DI + d];
        h2[i][1] = HF[(sbase * NS + 2 * i + 1) * DI + d];
    }

    const float* cb0 = xdbl + (size_t)b * LL * NX + k * CD;
    const float* ubase = ub + (size_t)b * LL * DI + d;
    float* ybase = ycomb + (size_t)b * LL * DI + d;
    const int l0 = c * CL;
    int p, hh;
    init_p(k, l0, p, hh);

    if (use_fast) {
        int pcur = p;
        float uv = ubase[(size_t)pcur * DI];
        for (int li = 0; li < CL; ++li) {
            adv_p(k, p, hh);
            int pn = (li + 1 < CL) ? p : pcur;
            float uv_next = ubase[(size_t)pn * DI];

            const float4* cp4 = (const float4*)(cb0 + (size_t)pcur * NX);
            float dq[12];
            *(float4*)(dq + 0) = cp4[0];
            *(float4*)(dq + 4) = cp4[1];
            *(float4*)(dq + 8) = cp4[2];
            float s = dtb;
#pragma unroll
            for (int r = 0; r < RR; ++r) s = fmaf(dtw[r], dq[r], s);
            float es = __expf(s);
            float dt = (s > 15.f) ? s : __logf(1.f + es);
            float E = __builtin_amdgcn_rcpf(1.f + es);
            float du = dt * uv;
            float bc[32];
            *(float4*)(bc + 0)  = cp4[3];
            *(float4*)(bc + 4)  = cp4[4];
            *(float4*)(bc + 8)  = cp4[5];
            *(float4*)(bc + 12) = cp4[6];
            *(float4*)(bc + 16) = cp4[7];
            *(float4*)(bc + 20) = cp4[8];
            *(float4*)(bc + 24) = cp4[9];
            *(float4*)(bc + 28) = cp4[10];
            const f32x2* b2 = (const f32x2*)bc;
            float ee = E * E;
            f32x2 pw2; pw2[0] = E; pw2[1] = ee;
            f32x2 ee2; ee2[0] = ee; ee2[1] = ee;
            f32x2 du2; du2[0] = du; du2[1] = du;
            f32x2 y2; y2[0] = 0.f; y2[1] = 0.f;
#pragma unroll
            for (int i = 0; i < 8; ++i) {
                h2[i] = EFMA(du2, b2[i], pw2 * h2[i]);
                y2 = EFMA(h2[i], b2[8 + i], y2);
                if (i < 7) pw2 = pw2 * ee2;
            }
            atomicAdd(ybase + (size_t)pcur * DI, fmaf(dsv, uv, y2[0] + y2[1]));
            pcur = p;
            uv = uv_next;
        }
    } else {
        for (int li = 0; li < CL; ++li) {
            int l = l0 + li;
            int pp = posmap(k, l);
            const float* cp = cb0 + (size_t)pp * NX;
            float s = dtb;
#pragma unroll
            for (int r = 0; r < RR; ++r) s = fmaf(dtw[r], cp[r], s);
            float dt = (s > 15.f) ? s : log1pf(__expf(s));
            float uv = ubase[(size_t)pp * DI];
            float du = dt * uv;
            float y = 0.f;
#pragma unroll
            for (int n = 0; n < NS; ++n) {
                float dA = __expf(dt * a[n]);
                float hv = h2[n >> 1][n & 1];
                hv = fmaf(du, cp[RR + n], dA * hv);
                h2[n >> 1][n & 1] = hv;
                y = fmaf(hv, cp[RR + NS + n], y);
            }
            atomicAdd(ybase + (size_t)pp * DI, fmaf(dsv, uv, y));
        }
    }
}

// ---------------- combine(LN over 384) * ln_w + ln_b, gate with bf16 z -> single bf16 plane ----------------
static __device__ __forceinline__ float waveRedSum(float v) {
#pragma unroll
    for (int o = 32; o; o >>= 1) v += __shfl_down(v, o);
    return v;
}

__global__ __launch_bounds__(128) void k_lngate(const float* __restrict__ ycomb,
                                                const u16* __restrict__ zb16,
                                                const float* __restrict__ lnw,
                                                const float* __restrict__ lnb,
                                                u16* __restrict__ ylnh) {
    int m = blockIdx.x;
    const float* yr = ycomb + (size_t)m * DI;
    float v[3];
    float s1 = 0.f, s2 = 0.f;
#pragma unroll
    for (int i = 0; i < 3; ++i) {
        v[i] = yr[threadIdx.x + (i << 7)];
        s1 += v[i];
        s2 = fmaf(v[i], v[i], s2);
    }
    s1 = waveRedSum(s1);
    s2 = waveRedSum(s2);
    __shared__ float p1[2], p2[2];
    int wid = threadIdx.x >> 6, lane = threadIdx.x & 63;
    if (lane == 0) { p1[wid] = s1; p2[wid] = s2; }
    __syncthreads();
    float S1 = p1[0] + p1[1];
    float S2 = p2[0] + p2[1];
    float mu = S1 * (1.f / DI);
    float var = S2 * (1.f / DI) - mu * mu;
    float rstd = rsqrtf(var + 1e-6f);
#pragma unroll
    for (int i = 0; i < 3; ++i) {
        int dd = threadIdx.x + (i << 7);
        float o = ((v[i] - mu) * rstd) * lnw[dd] + lnb[dd];
        float g = o * bf2f(zb16[(size_t)m * DI + dd]);
        ylnh[(size_t)m * DI + dd] = f2bf(g);
    }
}

extern "C" void kernel_launch(void* const* d_in, const int* in_sizes, int n_in,
                              void* d_out, int out_size, void* d_ws, size_t ws_size,
                              hipStream_t stream) {
    const float* x         = (const float*)d_in[0];
    const float* in_proj_w = (const float*)d_in[1];
    const float* conv_w    = (const float*)d_in[2];
    const float* conv_b    = (const float*)d_in[3];
    const float* x_proj_w  = (const float*)d_in[4];
    const float* dt_w      = (const float*)d_in[5];
    const float* dt_bias   = (const float*)d_in[6];
    const float* A_logs    = (const float*)d_in[7];
    const float* Ds        = (const float*)d_in[8];
    const float* ln_w      = (const float*)d_in[9];
    const float* ln_b      = (const float*)d_in[10];
    const float* out_proj_w= (const float*)d_in[11];
    float* out = (float*)d_out;
    float* ws  = (float*)d_ws;

    const size_t SZ = (size_t)MM * DI;            // 7,077,888 floats (28.3 MB)
    float* xi    = ws;
    u16*   zb16  = (u16*)(ws + SZ + SZ / 2);
    float* ub    = ws + 2 * SZ;
    float* xdbl  = ws + 3 * SZ;                   // MM*176 floats (13 MB), spatial layout
    float* ycomb = ws + 3 * SZ + (size_t)MM * NX;
    u16*   wpl   = (u16*)(ycomb + SZ);            // weight planes, 1.16 MB

    u16* wphi  = wpl;
    u16* xpwhi = wpl + 294912;
    u16* wohi  = wpl + 430080;

    u16* ylnh = (u16*)xi;                                  // xi region free post-scan
    float* HF = ws;                                        // 37.7MB
    float* SD = ws + (size_t)BB * NK * NC * NS * DI;       // +2.4MB -> ends < 1.5*SZ

    // merged weight converter
    k_cvtw<<<(W0N + W1N + W2N) / 4 / 256 + 1, 256, 0, stream>>>(in_proj_w, x_proj_w, out_proj_w, wpl);

    // in_proj GEMM (MFMA, fp32-A fused split, 2-term): xi fp32 + zb16 bf16
    k_gemm<768, CIN, 0, 1, 2><<<dim3(MM / 128, 12), 256, 0, stream>>>(
        (const u16*)x, nullptr, wphi, xi, (void*)zb16);

    // depthwise conv + silu (fp32 only)
    k_conv<<<MM, 192, 0, stream>>>(xi, conv_w, conv_b, ub);

    // xdbl GEMM (MFMA, fp32-A fused split, 2-term), spatial layout [b,p,176]
    k_gemm<NX, DI, 1, 1, 2><<<dim3(MM / 128, 3), 256, 0, stream>>>(
        (const u16*)ub, nullptr, xpwhi, xdbl, nullptr);

    // ycomb zero
    hipMemsetAsync(ycomb, 0, SZ * sizeof(float), stream);

    const int nscan = BB * NK * 3 * NC;   // 4608 blocks x 128 threads
    k_scan1<<<nscan, 128, 0, stream>>>(ub, xdbl, dt_w, dt_bias, A_logs, HF, SD);
    k_scan2<<<BB * NK * DI / 256, 256, 0, stream>>>(A_logs, HF, SD);
    k_scan3<<<nscan, 128, 0, stream>>>(ub, xdbl, dt_w, dt_bias, A_logs, Ds, HF, ycomb);

    k_lngate<<<MM, 128, 0, stream>>>(ycomb, zb16, ln_w, ln_b, ylnh);

    // out_proj GEMM (MFMA, 1-term bf16 A)
    k_gemm<CIN, DI, 2, 0, 1><<<dim3(MM / 128, 3), 256, 0, stream>>>(
        ylnh, nullptr, wohi, out, nullptr);
}

// Round 20
// 309.187 us; speedup vs baseline: 1.0196x; 1.0196x over previous
//
#include <hip/hip_runtime.h>

#define BB 8
#define HH 48
#define WW2 48
#define LL 2304      // HH*WW2
#define CIN 192
#define DI 384
#define NK 4
#define RR 12
#define NS 16
#define CD 44        // RR + 2*NS
#define NX 176       // NK*CD, xdbl row width (spatial layout)
#define MM 18432     // BB*LL
#define NC 48        // scan chunks
#define CL 48        // LL/NC

typedef unsigned short u16;
typedef __attribute__((ext_vector_type(8))) short s16x8;
typedef __attribute__((ext_vector_type(4))) float f32x4;
typedef __attribute__((ext_vector_type(2))) float f32x2;

#if __has_builtin(__builtin_elementwise_fma)
#define EFMA(a, b, c) __builtin_elementwise_fma((a), (b), (c))
#else
#define EFMA(a, b, c) ((a) * (b) + (c))
#endif

static __device__ __forceinline__ float siluf(float x) { return x / (1.f + __expf(-x)); }

static __device__ __forceinline__ u16 f2bf(float x) {
    unsigned u = __float_as_uint(x);
    return (u16)((u + 0x7FFFu + ((u >> 16) & 1u)) >> 16);
}
static __device__ __forceinline__ float bf2f(u16 h) {
    return __uint_as_float(((unsigned)h) << 16);
}

// scan index l (direction k) -> row-major spatial position
static __device__ __forceinline__ int posmap(int k, int l) {
    switch (k & 3) {
    case 0: return l;
    case 1: { int w = l / HH; int h = l - w * HH; return h * WW2 + w; }
    case 2: return LL - 1 - l;
    default: { int j = LL - 1 - l; int w = j / HH; int h = j - w * HH; return h * WW2 + w; }
    }
}

// ---------------- merged weight converter: 3 weights -> bf16 hi/lo planes ----------------
#define W0N 147456   // in_proj_w 768*192
#define W1N 67584    // x_proj_w 176*384
#define W2N 73728    // out_proj_w 192*384
__global__ __launch_bounds__(256) void k_cvtw(const float* __restrict__ w0,
                                              const float* __restrict__ w1,
                                              const float* __restrict__ w2,
                                              u16* __restrict__ wpl) {
    int i = (blockIdx.x * 256 + threadIdx.x) * 4;
    const float* src; u16* hi; u16* lo; int base;
    if (i < W0N)                { src = w0; hi = wpl;          lo = wpl + 147456; base = i; }
    else if (i < W0N + W1N)     { src = w1; hi = wpl + 294912; lo = wpl + 362496; base = i - W0N; }
    else if (i < W0N + W1N + W2N) { src = w2; hi = wpl + 430080; lo = wpl + 503808; base = i - W0N - W1N; }
    else return;
    float4 v = *(const float4*)(src + base);
    u16 h0 = f2bf(v.x), h1 = f2bf(v.y), h2 = f2bf(v.z), h3 = f2bf(v.w);
    hi[base + 0] = h0; hi[base + 1] = h1; hi[base + 2] = h2; hi[base + 3] = h3;
    lo[base + 0] = f2bf(v.x - bf2f(h0));
    lo[base + 1] = f2bf(v.y - bf2f(h1));
    lo[base + 2] = f2bf(v.z - bf2f(h2));
    lo[base + 3] = f2bf(v.w - bf2f(h3));
}

// ---------------- split-bf16 MFMA GEMM, tile 128x64: C(M x N) = A(M x K) @ B(N x K)^T ----------------
// EPI: 0 = in_proj (split xi fp32 / silu->zb bf16), 1 = store N=176 guarded, 2 = plain store (CIN).
// ACVT: 0 = A is bf16 plane(s); 1 = A fp32 split on the fly.
// SPLIT: 1 = Ah*Bh only; 2 = Al*Bh + Ah*Bh.
template<int N, int K, int EPI, int ACVT, int SPLIT>
__global__ __launch_bounds__(256) void k_gemm(const u16* __restrict__ Ahg,
                                              const u16* __restrict__ Alg,
                                              const u16* __restrict__ Bhg,
                                              float* __restrict__ O1,
                                              void* __restrict__ O2) {
    // u16 idx: Ah[0,4096) Al[4096,8192) Bh[8192,10240)
    __shared__ __align__(16) u16 lds[10240];
    const int m0 = blockIdx.x << 7;
    const int n0 = blockIdx.y << 6;
    const int t = threadIdx.x;
    const int lane = t & 63;
    const int w = t >> 6;
    const int wm = w & 1, wn = w >> 1;

    f32x4 acc[4][2];
#pragma unroll
    for (int mi = 0; mi < 4; ++mi)
#pragma unroll
        for (int ni = 0; ni < 2; ++ni)
#pragma unroll
            for (int r = 0; r < 4; ++r) acc[mi][ni][r] = 0.f;

    const int rA = lane & 15;
    const int kb = (lane >> 4) << 3;

    for (int k0 = 0; k0 < K; k0 += 32) {
#pragma unroll
        for (int rep = 0; rep < 2; ++rep) {
            int q = t + (rep << 8);
            int row = q >> 2;
            int kk = (q & 3) << 3;
            size_t ga = (size_t)(m0 + row) * K + k0 + kk;
            if (ACVT == 1) {
                const float* Af = (const float*)Ahg;
                float vv[8];
                *(float4*)(vv + 0) = *(const float4*)(Af + ga);
                *(float4*)(vv + 4) = *(const float4*)(Af + ga + 4);
                u16 hbuf[8], lbuf[8];
#pragma unroll
                for (int i = 0; i < 8; ++i) {
                    u16 h = f2bf(vv[i]);
                    hbuf[i] = h;
                    lbuf[i] = f2bf(vv[i] - bf2f(h));
                }
                *(uint4*)&lds[(row << 5) + kk] = *(uint4*)hbuf;
                if (SPLIT == 2)
                    *(uint4*)&lds[4096 + (row << 5) + kk] = *(uint4*)lbuf;
            } else {
                *(uint4*)&lds[(row << 5) + kk] = *(const uint4*)(Ahg + ga);
                if (SPLIT == 2)
                    *(uint4*)&lds[4096 + (row << 5) + kk] = *(const uint4*)(Alg + ga);
            }
        }
        {
            int row = t >> 2;
            int kk = (t & 3) << 3;
            int rg = n0 + row;
            if (N & 63) rg = (rg > N - 1) ? (N - 1) : rg;   // clamp (garbage cols unstored)
            size_t gb = (size_t)rg * K + k0 + kk;
            *(uint4*)&lds[8192 + (row << 5) + kk] = *(const uint4*)(Bhg + gb);
        }
        __syncthreads();

        s16x8 bh[2];
#pragma unroll
        for (int ni = 0; ni < 2; ++ni) {
            int c = (wn << 5) + (ni << 4) + rA;
            bh[ni] = *(const s16x8*)&lds[8192 + (c << 5) + kb];
        }
#pragma unroll
        for (int mi = 0; mi < 4; ++mi) {
            int rr = (wm << 6) + (mi << 4) + rA;
            s16x8 ah = *(const s16x8*)&lds[(rr << 5) + kb];
#pragma unroll
            for (int ni = 0; ni < 2; ++ni) {
                if (SPLIT == 2) {
                    s16x8 al = *(const s16x8*)&lds[4096 + (rr << 5) + kb];
                    acc[mi][ni] = __builtin_amdgcn_mfma_f32_16x16x32_bf16(al, bh[ni], acc[mi][ni], 0, 0, 0);
                }
                acc[mi][ni] = __builtin_amdgcn_mfma_f32_16x16x32_bf16(ah, bh[ni], acc[mi][ni], 0, 0, 0);
            }
        }
        __syncthreads();
    }

    const int rbase = (lane >> 4) << 2;
#pragma unroll
    for (int mi = 0; mi < 4; ++mi) {
#pragma unroll
        for (int ni = 0; ni < 2; ++ni) {
            int o = n0 + (wn << 5) + (ni << 4) + (lane & 15);
#pragma unroll
            for (int r = 0; r < 4; ++r) {
                int m = m0 + (wm << 6) + (mi << 4) + rbase + r;
                float v = acc[mi][ni][r];
                if (EPI == 0) {
                    if (o < DI) O1[(size_t)m * DI + o] = v;
                    else        ((u16*)O2)[(size_t)m * DI + (o - DI)] = f2bf(siluf(v));
                } else if (EPI == 1) {
                    if (o < NX) O1[(size_t)m * NX + o] = v;
                } else {
                    O1[(size_t)m * CIN + o] = v;
                }
            }
        }
    }
}

// ---------------- depthwise 3x3 conv + silu (NHWC, float2 over d) -> ub fp32 only ----------------
__global__ __launch_bounds__(192) void k_conv(const float* __restrict__ xi,
                                              const float* __restrict__ cw,
                                              const float* __restrict__ cb,
                                              float* __restrict__ ub) {
    int blk = blockIdx.x;
    int b = blk / LL, p = blk - b * LL;
    int h = p / WW2, w = p - h * WW2;
    int d2 = threadIdx.x * 2;

    float w0[9], w1[9];
#pragma unroll
    for (int i = 0; i < 9; ++i) {
        w0[i] = cw[d2 * 9 + i];
        w1[i] = cw[(d2 + 1) * 9 + i];
    }
    float ax = cb[d2], ay = cb[d2 + 1];
#pragma unroll
    for (int dh = -1; dh <= 1; ++dh) {
        int hh = h + dh;
        if (hh < 0 || hh >= HH) continue;
#pragma unroll
        for (int dw = -1; dw <= 1; ++dw) {
            int ww = w + dw;
            if (ww < 0 || ww >= WW2) continue;
            float2 v = *(const float2*)(xi + ((size_t)b * LL + hh * WW2 + ww) * DI + d2);
            int tap = (dh + 1) * 3 + (dw + 1);
            ax = fmaf(w0[tap], v.x, ax);
            ay = fmaf(w1[tap], v.y, ay);
        }
    }
    float2 o2; o2.x = siluf(ax); o2.y = siluf(ay);
    *(float2*)(ub + ((size_t)b * LL + p) * DI + d2) = o2;
}

// p-advance for one scan step (l -> l+1); k uniform per block
static __device__ __forceinline__ void adv_p(int k, int& p, int& hh) {
    if (k == 0) { ++p; }
    else if (k == 2) { --p; }
    else if (k == 1) {
        bool wrap = (hh == HH - 1);
        hh = wrap ? 0 : hh + 1;
        p += wrap ? -(LL - 1 - HH) : WW2;
    } else {
        bool wrap = (hh == 0);
        hh = wrap ? HH - 1 : hh - 1;
        p += wrap ? (LL - 1 - HH) : -WW2;
    }
}

static __device__ __forceinline__ void init_p(int k, int l0, int& p, int& hh) {
    hh = 0;
    if (k == 0) p = l0;
    else if (k == 2) p = LL - 1 - l0;
    else if (k == 1) { int w0 = l0 / HH; hh = l0 - w0 * HH; p = hh * WW2 + w0; }
    else { int j0 = LL - 1 - l0; int w0 = j0 / HH; hh = j0 - w0 * HH; p = hh * WW2 + w0; }
}

// scan grid decode: blk = ((k*3 + dblk)*NC + c)*8 + b  -> b = blk & 7 pins batch to XCD
static __device__ __forceinline__ void scan_decode(int blk, int& b, int& k, int& dblk, int& c) {
    b = blk & 7;
    int r = blk >> 3;
    c = r % NC;
    int t2 = r / NC;
    dblk = t2 % 3;
    k = t2 / 3;
}

// ---------------- scan S1: per-chunk local scan, store h_fin[16] + sum_dt ----------------
__global__ __launch_bounds__(128) void k_scan1(const float* __restrict__ ub,
                                               const float* __restrict__ xdbl,
                                               const float* __restrict__ dt_w,
                                               const float* __restrict__ dt_bias,
                                               const float* __restrict__ A_logs,
                                               float* __restrict__ HF,
                                               float* __restrict__ SD) {
    int b, k, dblk, c;
    scan_decode(blockIdx.x, b, k, dblk, c);
    int bk = (b << 2) | k;
    int d = (dblk << 7) + threadIdx.x;
    int kd = k * DI + d;

    float dtw[RR];
#pragma unroll
    for (int r = 0; r < RR; ++r) dtw[r] = dt_w[(size_t)kd * RR + r];
    float dtb = dt_bias[kd];
    float a[NS];
    bool fast = true;
#pragma unroll
    for (int n = 0; n < NS; ++n) {
        a[n] = -__expf(A_logs[(size_t)kd * NS + n]);
        fast = fast && (fabsf(a[n] + (float)(n + 1)) < 1e-3f * (float)(n + 1));
    }
    int use_fast = __all((int)fast);

    f32x2 h2[8];
#pragma unroll
    for (int i = 0; i < 8; ++i) { h2[i][0] = 0.f; h2[i][1] = 0.f; }
    float sumdt = 0.f;

    const float* cb0 = xdbl + (size_t)b * LL * NX + k * CD;   // row at spatial p: cb0 + p*NX
    const float* ubase = ub + (size_t)b * LL * DI + d;
    const int l0 = c * CL;
    int p, hh;
    init_p(k, l0, p, hh);

    if (use_fast) {
        for (int li = 0; li < CL; ++li) {
            const float4* cp4 = (const float4*)(cb0 + (size_t)p * NX);
            float dq[12];
            *(float4*)(dq + 0) = cp4[0];
            *(float4*)(dq + 4) = cp4[1];
            *(float4*)(dq + 8) = cp4[2];
            float s = dtb;
#pragma unroll
            for (int r = 0; r < RR; ++r) s = fmaf(dtw[r], dq[r], s);
            float es = __expf(s);
            float dt = (s > 15.f) ? s : __logf(1.f + es);
            float E = __builtin_amdgcn_rcpf(1.f + es);
            sumdt += dt;
            float uv = ubase[(size_t)p * DI];
            float du = dt * uv;
            float bb2[16];
            *(float4*)(bb2 + 0)  = cp4[3];
            *(float4*)(bb2 + 4)  = cp4[4];
            *(float4*)(bb2 + 8)  = cp4[5];
            *(float4*)(bb2 + 12) = cp4[6];
            const f32x2* b2 = (const f32x2*)bb2;
            float ee = E * E;
            f32x2 pw2; pw2[0] = E; pw2[1] = ee;
            f32x2 ee2; ee2[0] = ee; ee2[1] = ee;
            f32x2 du2; du2[0] = du; du2[1] = du;
#pragma unroll
            for (int i = 0; i < 8; ++i) {
                h2[i] = EFMA(du2, b2[i], pw2 * h2[i]);
                if (i < 7) pw2 = pw2 * ee2;
            }
            adv_p(k, p, hh);
        }
    } else {
        for (int li = 0; li < CL; ++li) {
            int l = l0 + li;
            int pp = posmap(k, l);
            const float* cp = cb0 + (size_t)pp * NX;
            float s = dtb;
#pragma unroll
            for (int r = 0; r < RR; ++r) s = fmaf(dtw[r], cp[r], s);
            float dt = (s > 15.f) ? s : log1pf(__expf(s));
            sumdt += dt;
            float uv = ubase[(size_t)pp * DI];
            float du = dt * uv;
#pragma unroll
            for (int n = 0; n < NS; ++n) {
                float dA = __expf(dt * a[n]);
                float hv = h2[n >> 1][n & 1];
                h2[n >> 1][n & 1] = fmaf(du, cp[RR + n], dA * hv);
            }
        }
    }
    size_t base = ((size_t)bk * NC + c);
#pragma unroll
    for (int i = 0; i < 8; ++i) {
        HF[(base * NS + 2 * i) * DI + d] = h2[i][0];
        HF[(base * NS + 2 * i + 1) * DI + d] = h2[i][1];
    }
    SD[base * DI + d] = sumdt;
}

// ---------------- scan S2: combine chunk states -> entry states (in place) ----------------
__global__ __launch_bounds__(256) void k_scan2(const float* __restrict__ A_logs,
                                               float* __restrict__ HF,
                                               const float* __restrict__ SD) {
    int idx = blockIdx.x * 256 + threadIdx.x;    // bk*DI + d
    int bk = idx / DI;
    int d = idx - bk * DI;
    int k = bk & 3;
    int kd = k * DI + d;

    float a[NS];
    bool fast = true;
#pragma unroll
    for (int n = 0; n < NS; ++n) {
        a[n] = -__expf(A_logs[(size_t)kd * NS + n]);
        fast = fast && (fabsf(a[n] + (float)(n + 1)) < 1e-3f * (float)(n + 1));
    }
    int use_fast = __all((int)fast);

    float H[NS];
#pragma unroll
    for (int n = 0; n < NS; ++n) H[n] = 0.f;

    for (int c = 0; c < NC; ++c) {
        size_t base = ((size_t)bk * NC + c);
        float sd = SD[base * DI + d];
        if (use_fast) {
            float E = __expf(-sd);
            float pw = 1.f;
#pragma unroll
            for (int n = 0; n < NS; ++n) {
                pw *= E;
                float hf = HF[(base * NS + n) * DI + d];
                HF[(base * NS + n) * DI + d] = H[n];
                H[n] = fmaf(pw, H[n], hf);
            }
        } else {
#pragma unroll
            for (int n = 0; n < NS; ++n) {
                float dec = __expf(a[n] * sd);
                float hf = HF[(base * NS + n) * DI + d];
                HF[(base * NS + n) * DI + d] = H[n];
                H[n] = fmaf(dec, H[n], hf);
            }
        }
    }
}

// ---------------- scan S3: per-chunk scan from entry state, scatter y ----------------
__global__ __launch_bounds__(128) void k_scan3(const float* __restrict__ ub,
                                               const float* __restrict__ xdbl,
                                               const float* __restrict__ dt_w,
                                               const float* __restrict__ dt_bias,
                                               const float* __restrict__ A_logs,
                                               const float* __restrict__ Ds,
                                               const float* __restrict__ HF,
                                               float* __restrict__ ycomb) {
    int b, k, dblk, c;
    scan_decode(blockIdx.x, b, k, dblk, c);
    int bk = (b << 2) | k;
    int d = (dblk << 7) + threadIdx.x;
    int kd = k * DI + d;

    float dtw[RR];
#pragma unroll
    for (int r = 0; r < RR; ++r) dtw[r] = dt_w[(size_t)kd * RR + r];
    float dtb = dt_bias[kd];
    float dsv = Ds[kd];
    float a[NS];
    bool fast = true;
#pragma unroll
    for (int n = 0; n < NS; ++n) {
        a[n] = -__expf(A_logs[(size_t)kd * NS + n]);
        fast = fast && (fabsf(a[n] + (float)(n + 1)) < 1e-3f * (float)(n + 1));
    }
    int use_fast = __all((int)fast);

    f32x2 h2[8];
    size_t sbase = ((size_t)bk * NC + c);
#pragma unroll
    for (int i = 0; i < 8; ++i) {
        h2[i][0] = HF[(sbase * NS + 2 * i) * DI + d];
        h2[i][1] = HF[(sbase * NS + 2 * i + 1) * DI + d];
    }

    const float* cb0 = xdbl + (size_t)b * LL * NX + k * CD;
    const float* ubase = ub + (size_t)b * LL * DI + d;
    float* ybase = ycomb + (size_t)b * LL * DI + d;
    const int l0 = c * CL;
    int p, hh;
    init_p(k, l0, p, hh);

    if (use_fast) {
        for (int li = 0; li < CL; ++li) {
            const float4* cp4 = (const float4*)(cb0 + (size_t)p * NX);
            float dq[12];
            *(float4*)(dq + 0) = cp4[0];
            *(float4*)(dq + 4) = cp4[1];
            *(float4*)(dq + 8) = cp4[2];
            float s = dtb;
#pragma unroll
            for (int r = 0; r < RR; ++r) s = fmaf(dtw[r], dq[r], s);
            float es = __expf(s);
            float dt = (s > 15.f) ? s : __logf(1.f + es);
            float E = __builtin_amdgcn_rcpf(1.f + es);
            float uv = ubase[(size_t)p * DI];
            float du = dt * uv;
            float bc[32];
            *(float4*)(bc + 0)  = cp4[3];
            *(float4*)(bc + 4)  = cp4[4];
            *(float4*)(bc + 8)  = cp4[5];
            *(float4*)(bc + 12) = cp4[6];
            *(float4*)(bc + 16) = cp4[7];
            *(float4*)(bc + 20) = cp4[8];
            *(float4*)(bc + 24) = cp4[9];
            *(float4*)(bc + 28) = cp4[10];
            const f32x2* b2 = (const f32x2*)bc;
            float ee = E * E;
            f32x2 pw2; pw2[0] = E; pw2[1] = ee;
            f32x2 ee2; ee2[0] = ee; ee2[1] = ee;
            f32x2 du2; du2[0] = du; du2[1] = du;
            f32x2 y2; y2[0] = 0.f; y2[1] = 0.f;
#pragma unroll
            for (int i = 0; i < 8; ++i) {
                h2[i] = EFMA(du2, b2[i], pw2 * h2[i]);
                y2 = EFMA(h2[i], b2[8 + i], y2);
                if (i < 7) pw2 = pw2 * ee2;
            }
            atomicAdd(ybase + (size_t)p * DI, fmaf(dsv, uv, y2[0] + y2[1]));
            adv_p(k, p, hh);
        }
    } else {
        for (int li = 0; li < CL; ++li) {
            int l = l0 + li;
            int pp = posmap(k, l);
            const float* cp = cb0 + (size_t)pp * NX;
            float s = dtb;
#pragma unroll
            for (int r = 0; r < RR; ++r) s = fmaf(dtw[r], cp[r], s);
            float dt = (s > 15.f) ? s : log1pf(__expf(s));
            float uv = ubase[(size_t)pp * DI];
            float du = dt * uv;
            float y = 0.f;
#pragma unroll
            for (int n = 0; n < NS; ++n) {
                float dA = __expf(dt * a[n]);
                float hv = h2[n >> 1][n & 1];
                hv = fmaf(du, cp[RR + n], dA * hv);
                h2[n >> 1][n & 1] = hv;
                y = fmaf(hv, cp[RR + NS + n], y);
            }
            atomicAdd(ybase + (size_t)pp * DI, fmaf(dsv, uv, y));
        }
    }
}

// ---------------- combine(LN over 384) * ln_w + ln_b, gate with bf16 z -> single bf16 plane ----------------
static __device__ __forceinline__ float waveRedSum(float v) {
#pragma unroll
    for (int o = 32; o; o >>= 1) v += __shfl_down(v, o);
    return v;
}

__global__ __launch_bounds__(128) void k_lngate(const float* __restrict__ ycomb,
                                                const u16* __restrict__ zb16,
                                                const float* __restrict__ lnw,
                                                const float* __restrict__ lnb,
                                                u16* __restrict__ ylnh) {
    int m = blockIdx.x;
    const float* yr = ycomb + (size_t)m * DI;
    float v[3];
    float s1 = 0.f, s2 = 0.f;
#pragma unroll
    for (int i = 0; i < 3; ++i) {
        v[i] = yr[threadIdx.x + (i << 7)];
        s1 += v[i];
        s2 = fmaf(v[i], v[i], s2);
    }
    s1 = waveRedSum(s1);
    s2 = waveRedSum(s2);
    __shared__ float p1[2], p2[2];
    int wid = threadIdx.x >> 6, lane = threadIdx.x & 63;
    if (lane == 0) { p1[wid] = s1; p2[wid] = s2; }
    __syncthreads();
    float S1 = p1[0] + p1[1];
    float S2 = p2[0] + p2[1];
    float mu = S1 * (1.f / DI);
    float var = S2 * (1.f / DI) - mu * mu;
    float rstd = rsqrtf(var + 1e-6f);
#pragma unroll
    for (int i = 0; i < 3; ++i) {
        int dd = threadIdx.x + (i << 7);
        float o = ((v[i] - mu) * rstd) * lnw[dd] + lnb[dd];
        float g = o * bf2f(zb16[(size_t)m * DI + dd]);
        ylnh[(size_t)m * DI + dd] = f2bf(g);
    }
}

extern "C" void kernel_launch(void* const* d_in, const int* in_sizes, int n_in,
                              void* d_out, int out_size, void* d_ws, size_t ws_size,
                              hipStream_t stream) {
    const float* x         = (const float*)d_in[0];
    const float* in_proj_w = (const float*)d_in[1];
    const float* conv_w    = (const float*)d_in[2];
    const float* conv_b    = (const float*)d_in[3];
    const float* x_proj_w  = (const float*)d_in[4];
    const float* dt_w      = (const float*)d_in[5];
    const float* dt_bias   = (const float*)d_in[6];
    const float* A_logs    = (const float*)d_in[7];
    const float* Ds        = (const float*)d_in[8];
    const float* ln_w      = (const float*)d_in[9];
    const float* ln_b      = (const float*)d_in[10];
    const float* out_proj_w= (const float*)d_in[11];
    float* out = (float*)d_out;
    float* ws  = (float*)d_ws;

    const size_t SZ = (size_t)MM * DI;            // 7,077,888 floats (28.3 MB)
    float* xi    = ws;
    u16*   zb16  = (u16*)(ws + SZ + SZ / 2);
    float* ub    = ws + 2 * SZ;
    float* xdbl  = ws + 3 * SZ;                   // MM*176 floats (13 MB), spatial layout
    float* ycomb = ws + 3 * SZ + (size_t)MM * NX;
    u16*   wpl   = (u16*)(ycomb + SZ);            // weight planes, 1.16 MB

    u16* wphi  = wpl;
    u16* xpwhi = wpl + 294912;
    u16* wohi  = wpl + 430080;

    u16* ylnh = (u16*)xi;                                  // xi region free post-scan
    float* HF = ws;                                        // 37.7MB
    float* SD = ws + (size_t)BB * NK * NC * NS * DI;       // +2.4MB -> ends < 1.5*SZ

    // merged weight converter
    k_cvtw<<<(W0N + W1N + W2N) / 4 / 256 + 1, 256, 0, stream>>>(in_proj_w, x_proj_w, out_proj_w, wpl);

    // in_proj GEMM (MFMA, fp32-A fused split, 2-term): xi fp32 + zb16 bf16
    k_gemm<768, CIN, 0, 1, 2><<<dim3(MM / 128, 12), 256, 0, stream>>>(
        (const u16*)x, nullptr, wphi, xi, (void*)zb16);

    // depthwise conv + silu (fp32 only)
    k_conv<<<MM, 192, 0, stream>>>(xi, conv_w, conv_b, ub);

    // xdbl GEMM (MFMA, fp32-A fused split, 2-term), spatial layout [b,p,176]
    k_gemm<NX, DI, 1, 1, 2><<<dim3(MM / 128, 3), 256, 0, stream>>>(
        (const u16*)ub, nullptr, xpwhi, xdbl, nullptr);

    // ycomb zero
    hipMemsetAsync(ycomb, 0, SZ * sizeof(float), stream);

    const int nscan = BB * NK * 3 * NC;   // 4608 blocks x 128 threads
    k_scan1<<<nscan, 128, 0, stream>>>(ub, xdbl, dt_w, dt_bias, A_logs, HF, SD);
    k_scan2<<<BB * NK * DI / 256, 256, 0, stream>>>(A_logs, HF, SD);
    k_scan3<<<nscan, 128, 0, stream>>>(ub, xdbl, dt_w, dt_bias, A_logs, Ds, HF, ycomb);

    k_lngate<<<MM, 128, 0, stream>>>(ycomb, zb16, ln_w, ln_b, ylnh);

    // out_proj GEMM (MFMA, 1-term bf16 A)
    k_gemm<CIN, DI, 2, 0, 1><<<dim3(MM / 128, 3), 256, 0, stream>>>(
        ylnh, nullptr, wohi, out, nullptr);
}